// Round 2
// baseline (2295.413 us; speedup 1.0000x reference)
//
#include <hip/hip_runtime.h>
#include <hip/hip_bf16.h>
#include <math.h>

// ---------------- problem constants ----------------
#define BB 32
#define NN 512
#define BN 16384          // BB*NN
#define DD 1024
#define HID 512
#define G4 2048           // 4*HID
#define HLEN 15
#define IND 4
#define EPS 1e-5f

typedef __bf16 v8bf __attribute__((ext_vector_type(8)));
typedef float  v4f  __attribute__((ext_vector_type(4)));

// fast transcendentals: v_exp_f32 + v_rcp_f32 (rel err ~1e-6, fine vs 0.11 threshold)
#define LOG2E 1.44269504f
__device__ __forceinline__ float sigmf(float x) {
    return __builtin_amdgcn_rcpf(1.0f + __builtin_amdgcn_exp2f(-LOG2E * x));
}
__device__ __forceinline__ float tanh_fast(float x) {
    return 1.0f - 2.0f * __builtin_amdgcn_rcpf(1.0f + __builtin_amdgcn_exp2f(2.0f * LOG2E * x));
}

// ---------------- weight prep ----------------
// whh_b: NATIVE layout bf16 2048x512 (gate blocks i,f,g,o of 512 rows each);
// wrel_b: bf16 1024x512; wih_i: unit-interleaved fp32 2048x4; bsum: b_ih+b_hh interleaved.
__global__ void convert_w(const float* __restrict__ Whh, const float* __restrict__ Wrel,
                          const float* __restrict__ Wih, const float* __restrict__ bih,
                          const float* __restrict__ bhh,
                          __bf16* __restrict__ whh_b, __bf16* __restrict__ wrel_b,
                          float* __restrict__ wih_i, float* __restrict__ bsum) {
    int i = blockIdx.x * 256 + threadIdx.x;
    if (i < G4 * HID) whh_b[i] = (__bf16)Whh[i];
    if (i < DD * HID) wrel_b[i] = (__bf16)Wrel[i];
    if (i < G4) {
        int uu = i >> 2, gi = i & 3;
        int src = gi * HID + uu;
        wih_i[i * 4 + 0] = Wih[src * 4 + 0];
        wih_i[i * 4 + 1] = Wih[src * 4 + 1];
        wih_i[i * 4 + 2] = Wih[src * 4 + 2];
        wih_i[i * 4 + 3] = Wih[src * 4 + 3];
        bsum[i] = bih[src] + bhh[src];
    }
}

// ---------------- per-batch gate alpha ----------------
__global__ void alpha_kernel(const float* __restrict__ es, const float* __restrict__ gc,
                             const float* __restrict__ W_g1, const float* __restrict__ b_g1,
                             const float* __restrict__ W_g2, const float* __restrict__ b_g2,
                             float* __restrict__ alpha) {
    int b = threadIdx.x;
    if (b >= BB) return;
    float c0 = es[b], c1 = gc[b];
    float acc = b_g2[0];
    for (int k = 0; k < 16; ++k) {
        float hk = c0 * W_g1[k * 2] + c1 * W_g1[k * 2 + 1] + b_g1[k];
        hk = fmaxf(hk, 0.0f);
        acc += hk * W_g2[k];
    }
    alpha[b] = 1.0f / (1.0f + expf(-acc));   // once, keep accurate
}

// ---------------- t=0 cell (h0 = c0 = 0 -> gates from input only) ----------------
__global__ __launch_bounds__(256) void lstm_cell0(const float* __restrict__ traj,
                                                  const float* __restrict__ wih_i,
                                                  const float* __restrict__ bsum,
                                                  float* __restrict__ c,
                                                  __bf16* __restrict__ h) {
    int idx = blockIdx.x * 256 + threadIdx.x;   // row*512 + u
    int row = idx >> 9;
    float4 x = *(const float4*)(traj + (size_t)row * (HLEN * IND));   // t = 0, 16B aligned
    int u = idx & 511;
    float g[4];
    #pragma unroll
    for (int gi = 0; gi < 4; ++gi) {
        int j = u * 4 + gi;
        float4 w = *(const float4*)(wih_i + (size_t)j * 4);
        g[gi] = bsum[j] + w.x * x.x + w.y * x.y + w.z * x.z + w.w * x.w;
    }
    float ig = sigmf(g[0]);
    float gg = tanh_fast(g[2]);
    float og = sigmf(g[3]);
    float cn = ig * gg;                    // f*c0 = 0
    c[idx] = cn;
    h[idx] = (__bf16)(og * tanh_fast(cn));
}

// ---------------- fused GEMM + LSTM cell, LDS-FREE ----------------
// All operand fragments loaded directly from global (L1/L2). A wave's dwordx4
// fragment load hits exactly 16 distinct 64B lines (4 lanes per line) -> fully
// coalesced. No barriers, no LDS, no staging; unrolled k-loop folds all offsets
// into immediates on 8 base pointers. B-frag j == gate j (native W_hh layout),
// so each lane holds all 4 gates of its unit in acc[i][0..3][r].
__global__ __launch_bounds__(256) void gemm_lstm(const __bf16* __restrict__ A,
                                                 const __bf16* __restrict__ Bm,
                                                 const float* __restrict__ traj,
                                                 const float* __restrict__ wih_i,
                                                 const float* __restrict__ bsum,
                                                 float* __restrict__ c,
                                                 __bf16* __restrict__ h_out,
                                                 int t) {
    const int K = HID;
    const int tid  = threadIdx.x;
    const int lane = tid & 63;
    const int wave = tid >> 6;
    const int wm   = (wave & 1) * 64;        // row half
    const int wn16 = (wave >> 1) * 16;       // unit half within the block's 32 units
    const int bn = blockIdx.x;               // units [bn*32, bn*32+32)
    const int bm = blockIdx.y;
    const int u0 = bn * 32;

    const int mrow = lane & 15;
    const int kq   = (lane >> 4) * 8;
    const int u_glob = u0 + wn16 + mrow;

    v4f acc[4][4] = {};

    // 8 per-lane base pointers; all k-offsets become compile-time immediates.
    const __bf16* pa[4];
    const __bf16* pb[4];
    #pragma unroll
    for (int i = 0; i < 4; ++i)
        pa[i] = A + (size_t)(bm * 128 + wm + i * 16 + mrow) * K + kq;
    #pragma unroll
    for (int j = 0; j < 4; ++j)
        pb[j] = Bm + (size_t)(j * 512 + u_glob) * K + kq;   // gate j, unit u_glob

    v8bf aC[4], bC[4], aN[4], bN[4];
    #pragma unroll
    for (int i = 0; i < 4; ++i) { aC[i] = *(const v8bf*)(pa[i]); bC[i] = *(const v8bf*)(pb[i]); }

    #pragma unroll
    for (int k0 = 0; k0 < K; k0 += 64) {
        #pragma unroll
        for (int i = 0; i < 4; ++i) {
            aN[i] = *(const v8bf*)(pa[i] + k0 + 32);
            bN[i] = *(const v8bf*)(pb[i] + k0 + 32);
        }
        #pragma unroll
        for (int i = 0; i < 4; ++i)
            #pragma unroll
            for (int j = 0; j < 4; ++j)
                acc[i][j] = __builtin_amdgcn_mfma_f32_16x16x32_bf16(aC[i], bC[j], acc[i][j], 0, 0, 0);
        if (k0 + 64 < K) {
            #pragma unroll
            for (int i = 0; i < 4; ++i) {
                aC[i] = *(const v8bf*)(pa[i] + k0 + 64);
                bC[i] = *(const v8bf*)(pb[i] + k0 + 64);
            }
        }
        #pragma unroll
        for (int i = 0; i < 4; ++i)
            #pragma unroll
            for (int j = 0; j < 4; ++j)
                acc[i][j] = __builtin_amdgcn_mfma_f32_16x16x32_bf16(aN[i], bN[j], acc[i][j], 0, 0, 0);
    }

    // ---- register-only cell update: lane owns unit u_glob, rows wm+i*16+crow4+r ----
    const int crow4 = (lane >> 4) * 4;
    float wv[4][4], bs4[4];
    #pragma unroll
    for (int gi = 0; gi < 4; ++gi) {
        float4 wp = *(const float4*)(wih_i + (size_t)(u_glob * 4 + gi) * 4);
        wv[gi][0] = wp.x; wv[gi][1] = wp.y; wv[gi][2] = wp.z; wv[gi][3] = wp.w;
        bs4[gi] = bsum[u_glob * 4 + gi];
    }
    #pragma unroll
    for (int i = 0; i < 4; ++i) {
        const int growb = bm * 128 + wm + i * 16 + crow4;
        #pragma unroll
        for (int r = 0; r < 4; ++r) {
            const int grow = growb + r;
            const float4 x = *(const float4*)(traj + (size_t)grow * (HLEN * IND) + t * IND);
            float g[4];
            #pragma unroll
            for (int gi = 0; gi < 4; ++gi)
                g[gi] = acc[i][gi][r] + bs4[gi]
                      + wv[gi][0] * x.x + wv[gi][1] * x.y + wv[gi][2] * x.z + wv[gi][3] * x.w;
            float ig = sigmf(g[0]);
            float fg = sigmf(g[1]);
            float gg = tanh_fast(g[2]);
            float og = sigmf(g[3]);
            size_t ci = (size_t)grow * HID + u_glob;
            float cn = fg * c[ci] + ig * gg;
            c[ci] = cn;
            h_out[ci] = (__bf16)(og * tanh_fast(cn));
        }
    }
}

// ---------------- projection GEMM: hrel(16384x1024 bf16) = h @ W_rel^T, LDS-free ----------------
__global__ __launch_bounds__(256) void gemm_proj(const __bf16* __restrict__ A,
                                                 const __bf16* __restrict__ Bm,
                                                 __bf16* __restrict__ Cout) {
    const int K = HID, Nn = DD;
    const int tid  = threadIdx.x;
    const int lane = tid & 63;
    const int wave = tid >> 6;
    const int wm = (wave & 1) * 64;
    const int wn = (wave >> 1) * 64;
    const int bn = blockIdx.x;
    const int bm = blockIdx.y;

    const int mrow = lane & 15;
    const int kq   = (lane >> 4) * 8;

    v4f acc[4][4] = {};

    const __bf16* pa[4];
    const __bf16* pb[4];
    #pragma unroll
    for (int i = 0; i < 4; ++i)
        pa[i] = A + (size_t)(bm * 128 + wm + i * 16 + mrow) * K + kq;
    #pragma unroll
    for (int j = 0; j < 4; ++j)
        pb[j] = Bm + (size_t)(bn * 128 + wn + j * 16 + mrow) * K + kq;

    v8bf aC[4], bC[4], aN[4], bN[4];
    #pragma unroll
    for (int i = 0; i < 4; ++i) { aC[i] = *(const v8bf*)(pa[i]); bC[i] = *(const v8bf*)(pb[i]); }

    #pragma unroll
    for (int k0 = 0; k0 < K; k0 += 64) {
        #pragma unroll
        for (int i = 0; i < 4; ++i) {
            aN[i] = *(const v8bf*)(pa[i] + k0 + 32);
            bN[i] = *(const v8bf*)(pb[i] + k0 + 32);
        }
        #pragma unroll
        for (int i = 0; i < 4; ++i)
            #pragma unroll
            for (int j = 0; j < 4; ++j)
                acc[i][j] = __builtin_amdgcn_mfma_f32_16x16x32_bf16(aC[i], bC[j], acc[i][j], 0, 0, 0);
        if (k0 + 64 < K) {
            #pragma unroll
            for (int i = 0; i < 4; ++i) {
                aC[i] = *(const v8bf*)(pa[i] + k0 + 64);
                bC[i] = *(const v8bf*)(pb[i] + k0 + 64);
            }
        }
        #pragma unroll
        for (int i = 0; i < 4; ++i)
            #pragma unroll
            for (int j = 0; j < 4; ++j)
                acc[i][j] = __builtin_amdgcn_mfma_f32_16x16x32_bf16(aN[i], bN[j], acc[i][j], 0, 0, 0);
    }

    const int ccol  = lane & 15;
    const int crow4 = (lane >> 4) * 4;
    #pragma unroll
    for (int i = 0; i < 4; ++i)
        #pragma unroll
        for (int j = 0; j < 4; ++j) {
            int gm = bm * 128 + wm + i * 16 + crow4;
            int gn = bn * 128 + wn + j * 16 + ccol;
            #pragma unroll
            for (int r = 0; r < 4; ++r)
                Cout[(size_t)(gm + r) * Nn + gn] = (__bf16)acc[i][j][r];
        }
}

// ---------------- fused gate-mix + residual + LayerNorm ----------------
__global__ __launch_bounds__(256) void fuse_ln(const float* __restrict__ tokens,
                                               const __bf16* __restrict__ hrel,
                                               const float* __restrict__ habs_in,
                                               const float* __restrict__ W_abs,
                                               const float* __restrict__ alpha,
                                               const float* __restrict__ gamma,
                                               const float* __restrict__ beta,
                                               float* __restrict__ out) {
    const int row = blockIdx.x;
    const int b   = row >> 9;
    const float al = alpha[b];
    const float a0 = habs_in[(size_t)row * 2];
    const float a1 = habs_in[(size_t)row * 2 + 1];
    const int tid  = threadIdx.x;
    const int lane = tid & 63;
    const int wave = tid >> 6;

    __shared__ float red[4];

    float x[4];
    float s = 0.0f;
    #pragma unroll
    for (int q = 0; q < 4; ++q) {
        int dcol = tid + q * 256;
        float habs = a0 * W_abs[dcol * 2] + a1 * W_abs[dcol * 2 + 1];
        float v = tokens[(size_t)row * DD + dcol]
                + al * (float)hrel[(size_t)row * DD + dcol]
                + (1.0f - al) * habs;
        x[q] = v;
        s += v;
    }
    #pragma unroll
    for (int off = 32; off > 0; off >>= 1) s += __shfl_down(s, off);
    if (lane == 0) red[wave] = s;
    __syncthreads();
    float mu = (red[0] + red[1] + red[2] + red[3]) * (1.0f / DD);

    float vs = 0.0f;
    #pragma unroll
    for (int q = 0; q < 4; ++q) {
        float d = x[q] - mu;
        vs += d * d;
    }
    #pragma unroll
    for (int off = 32; off > 0; off >>= 1) vs += __shfl_down(vs, off);
    __syncthreads();
    if (lane == 0) red[wave] = vs;
    __syncthreads();
    float var = (red[0] + red[1] + red[2] + red[3]) * (1.0f / DD);
    float rstd = rsqrtf(var + EPS);

    #pragma unroll
    for (int q = 0; q < 4; ++q) {
        int dcol = tid + q * 256;
        out[(size_t)row * DD + dcol] = (x[q] - mu) * rstd * gamma[dcol] + beta[dcol];
    }
}

// ---------------- host launch ----------------
extern "C" void kernel_launch(void* const* d_in, const int* in_sizes, int n_in,
                              void* d_out, int out_size, void* d_ws, size_t ws_size,
                              hipStream_t stream) {
    const float* tokens   = (const float*)d_in[0];
    const float* traj     = (const float*)d_in[1];
    const float* habs     = (const float*)d_in[2];
    const float* espeed   = (const float*)d_in[3];
    const float* gconf    = (const float*)d_in[4];
    const float* W_ih     = (const float*)d_in[5];
    const float* W_hh     = (const float*)d_in[6];
    const float* b_ih     = (const float*)d_in[7];
    const float* b_hh     = (const float*)d_in[8];
    const float* W_rel    = (const float*)d_in[9];
    const float* W_abs    = (const float*)d_in[10];
    const float* W_g1     = (const float*)d_in[11];
    const float* b_g1     = (const float*)d_in[12];
    const float* W_g2     = (const float*)d_in[13];
    const float* b_g2     = (const float*)d_in[14];
    const float* gamma    = (const float*)d_in[15];
    const float* beta     = (const float*)d_in[16];
    float* out = (float*)d_out;

    char* ws = (char*)d_ws;
    size_t off = 0;
    __bf16* whh_b  = (__bf16*)(ws + off); off += (size_t)G4 * HID * 2;     // 2 MB
    __bf16* wrel_b = (__bf16*)(ws + off); off += (size_t)DD * HID * 2;     // 1 MB
    float*  wih_i  = (float*)(ws + off);  off += (size_t)G4 * 4 * 4;       // 32 KB
    float*  bsum   = (float*)(ws + off);  off += (size_t)G4 * 4;           // 8 KB
    __bf16* h0     = (__bf16*)(ws + off); off += (size_t)BN * HID * 2;     // 16 MB
    __bf16* h1     = (__bf16*)(ws + off); off += (size_t)BN * HID * 2;     // 16 MB
    float*  c      = (float*)(ws + off);  off += (size_t)BN * HID * 4;     // 32 MB
    __bf16* hrel   = (__bf16*)(ws + off); off += (size_t)BN * DD * 2;      // 32 MB
    float*  alpha  = (float*)(ws + off);  off += 256;

    convert_w<<<(G4 * HID + 255) / 256, 256, 0, stream>>>(W_hh, W_rel, W_ih, b_ih, b_hh,
                                                          whh_b, wrel_b, wih_i, bsum);
    alpha_kernel<<<1, 64, 0, stream>>>(espeed, gconf, W_g1, b_g1, W_g2, b_g2, alpha);
    lstm_cell0<<<(BN * HID) / 256, 256, 0, stream>>>(traj, wih_i, bsum, c, h0);

    __bf16* hbuf[2] = {h0, h1};
    for (int t = 1; t < HLEN; ++t) {
        const __bf16* hin = hbuf[(t + 1) & 1];
        __bf16* hout = hbuf[t & 1];
        gemm_lstm<<<dim3(G4 / 128, BN / 128), 256, 0, stream>>>(hin, whh_b, traj, wih_i, bsum,
                                                                c, hout, t);
    }
    // final h after t=14 is in hbuf[14&1] = h0
    gemm_proj<<<dim3(DD / 128, BN / 128), 256, 0, stream>>>(h0, wrel_b, hrel);
    fuse_ln<<<BN, 256, 0, stream>>>(tokens, hrel, habs, W_abs, alpha, gamma, beta, out);
}

// Round 3
// 1285.020 us; speedup vs baseline: 1.7863x; 1.7863x over previous
//
#include <hip/hip_runtime.h>
#include <hip/hip_bf16.h>
#include <math.h>

// ---------------- problem constants ----------------
#define BB 32
#define NN 512
#define BN 16384          // BB*NN
#define DD 1024
#define HID 512
#define G4 2048           // 4*HID
#define HLEN 15
#define IND 4
#define EPS 1e-5f

typedef __bf16 v8bf __attribute__((ext_vector_type(8)));
typedef float  v4f  __attribute__((ext_vector_type(4)));

__device__ __forceinline__ void async_copy16(const __bf16* gsrc, __bf16* ldst) {
    __builtin_amdgcn_global_load_lds(
        (const __attribute__((address_space(1))) void*)gsrc,
        (__attribute__((address_space(3))) void*)ldst, 16, 0, 0);
}

#define VMCNT4 asm volatile("s_waitcnt vmcnt(4)" ::: "memory")
#define VMCNT0 asm volatile("s_waitcnt vmcnt(0)" ::: "memory")
#define LGKM0  asm volatile("s_waitcnt lgkmcnt(0)" ::: "memory")
#define MEMFENCE asm volatile("" ::: "memory")

// fast transcendentals: v_exp_f32 + v_rcp_f32 (rel err ~1e-6, fine vs 0.11 threshold)
#define LOG2E 1.44269504f
__device__ __forceinline__ float sigmf(float x) {
    return __builtin_amdgcn_rcpf(1.0f + __builtin_amdgcn_exp2f(-LOG2E * x));
}
__device__ __forceinline__ float tanh_fast(float x) {
    return 1.0f - 2.0f * __builtin_amdgcn_rcpf(1.0f + __builtin_amdgcn_exp2f(2.0f * LOG2E * x));
}

// ---------------- weight prep ----------------
// whh_b: NATIVE layout bf16 2048x512 (gate blocks i,f,g,o of 512 rows each);
// wrel_b: bf16 1024x512; wih_i: unit-interleaved fp32 2048x4; bsum: b_ih+b_hh interleaved.
__global__ void convert_w(const float* __restrict__ Whh, const float* __restrict__ Wrel,
                          const float* __restrict__ Wih, const float* __restrict__ bih,
                          const float* __restrict__ bhh,
                          __bf16* __restrict__ whh_b, __bf16* __restrict__ wrel_b,
                          float* __restrict__ wih_i, float* __restrict__ bsum) {
    int i = blockIdx.x * 256 + threadIdx.x;
    if (i < G4 * HID) whh_b[i] = (__bf16)Whh[i];
    if (i < DD * HID) wrel_b[i] = (__bf16)Wrel[i];
    if (i < G4) {
        int uu = i >> 2, gi = i & 3;
        int src = gi * HID + uu;
        wih_i[i * 4 + 0] = Wih[src * 4 + 0];
        wih_i[i * 4 + 1] = Wih[src * 4 + 1];
        wih_i[i * 4 + 2] = Wih[src * 4 + 2];
        wih_i[i * 4 + 3] = Wih[src * 4 + 3];
        bsum[i] = bih[src] + bhh[src];
    }
}

// ---------------- per-batch gate alpha ----------------
__global__ void alpha_kernel(const float* __restrict__ es, const float* __restrict__ gc,
                             const float* __restrict__ W_g1, const float* __restrict__ b_g1,
                             const float* __restrict__ W_g2, const float* __restrict__ b_g2,
                             float* __restrict__ alpha) {
    int b = threadIdx.x;
    if (b >= BB) return;
    float c0 = es[b], c1 = gc[b];
    float acc = b_g2[0];
    for (int k = 0; k < 16; ++k) {
        float hk = c0 * W_g1[k * 2] + c1 * W_g1[k * 2 + 1] + b_g1[k];
        hk = fmaxf(hk, 0.0f);
        acc += hk * W_g2[k];
    }
    alpha[b] = 1.0f / (1.0f + expf(-acc));   // once, keep accurate
}

// ---------------- t=0 cell (h0 = c0 = 0 -> gates from input only) ----------------
__global__ __launch_bounds__(256) void lstm_cell0(const float* __restrict__ traj,
                                                  const float* __restrict__ wih_i,
                                                  const float* __restrict__ bsum,
                                                  float* __restrict__ c,
                                                  __bf16* __restrict__ h) {
    int idx = blockIdx.x * 256 + threadIdx.x;   // row*512 + u
    int row = idx >> 9;
    float4 x = *(const float4*)(traj + (size_t)row * (HLEN * IND));   // t = 0, 16B aligned
    int u = idx & 511;
    float g[4];
    #pragma unroll
    for (int gi = 0; gi < 4; ++gi) {
        int j = u * 4 + gi;
        float4 w = *(const float4*)(wih_i + (size_t)j * 4);
        g[gi] = bsum[j] + w.x * x.x + w.y * x.y + w.z * x.z + w.w * x.w;
    }
    float ig = sigmf(g[0]);
    float gg = tanh_fast(g[2]);
    float og = sigmf(g[3]);
    float cn = ig * gg;                    // f*c0 = 0
    c[idx] = cn;
    h[idx] = (__bf16)(og * tanh_fast(cn));
}

// ---------------- fused GEMM + LSTM cell: counted-vmcnt pipeline + XOR swizzle ----------------
// LDS tiles [128][32] bf16, chunk-swizzled: physical 16B-chunk p = logical_chunk ^ (row&3).
// global_load_lds dest stays LINEAR; the per-lane GLOBAL source chunk is pre-swizzled
// (rule: both-sides-or-neither). Fragment reads use pc = (lane>>4)^(mrow&3) -> 2 lanes/bank.
// Pipeline: stage tile k+1, s_waitcnt vmcnt(4) (tile k landed, k+1 stays in flight),
// raw s_barrier, ds_read, lgkmcnt(0), release barrier, MFMA. Full drain only at tail.
__global__ __launch_bounds__(256) void gemm_lstm(const __bf16* __restrict__ A,
                                                 const __bf16* __restrict__ Bm,
                                                 const float* __restrict__ traj,
                                                 const float* __restrict__ wih_i,
                                                 const float* __restrict__ bsum,
                                                 float* __restrict__ c,
                                                 __bf16* __restrict__ h_out,
                                                 int t) {
    __shared__ __bf16 sA[2][128][32];   // 16 KB
    __shared__ __bf16 sB[2][128][32];   // 16 KB : rows = gate*32 + (u-u0)
    const int K = HID;
    const int tid  = threadIdx.x;
    const int lane = tid & 63;
    const int wave = tid >> 6;
    const int wm   = (wave & 1) * 64;        // row half
    const int wn16 = (wave >> 1) * 16;       // unit half within the block's 32 units
    const int bn = blockIdx.x;               // units [bn*32, bn*32+32)
    const int bm = blockIdx.y;
    const int u0 = bn * 32;

    v4f acc[4][4] = {};

    const int srow   = tid >> 2;                       // staged row 0..63 (and +64 copy)
    const int schunk = (tid & 3) ^ (srow & 3);         // pre-swizzled source chunk

    const __bf16* gA = A + (size_t)(bm * 128 + srow) * K + schunk * 8;
    // B tile row = gate*32 + uoff; rows srow<64 cover gates 0..1, +64 => +1024 global rows.
    const __bf16* gB = Bm + (size_t)((srow >> 5) * 512 + u0 + (srow & 31)) * K + schunk * 8;
    __bf16* lA = &sA[0][0][0] + wave * 512;   // wave-uniform base; HW scatters lane*16B
    __bf16* lB = &sB[0][0][0] + wave * 512;

    const int mrow = lane & 15;
    const int pc   = ((lane >> 4) ^ (mrow & 3)) * 8;   // swizzled read chunk offset (elems)

    #define STAGE(buf, kt)                                        \
        do {                                                      \
            const __bf16* pA_ = gA + (kt) * 32;                   \
            const __bf16* pB_ = gB + (kt) * 32;                   \
            __bf16* dA_ = lA + (buf) * 4096;                      \
            __bf16* dB_ = lB + (buf) * 4096;                      \
            async_copy16(pA_,            dA_);                    \
            async_copy16(pA_ + 64 * K,   dA_ + 2048);             \
            async_copy16(pB_,            dB_);                    \
            async_copy16(pB_ + 1024 * K, dB_ + 2048);             \
        } while (0)

    STAGE(0, 0);
    #pragma unroll
    for (int k = 0; k < 15; ++k) {
        const int cur = k & 1;
        STAGE(cur ^ 1, k + 1);
        VMCNT4;                              // tile k landed; tile k+1 stays in flight
        __builtin_amdgcn_s_barrier();
        MEMFENCE;
        v8bf af[4], bfr[4];
        #pragma unroll
        for (int i = 0; i < 4; ++i) af[i]  = *(v8bf*)&sA[cur][wm + i * 16 + mrow][pc];
        #pragma unroll
        for (int j = 0; j < 4; ++j) bfr[j] = *(v8bf*)&sB[cur][j * 32 + wn16 + mrow][pc];
        LGKM0;                               // my reads done before others restage cur
        __builtin_amdgcn_s_barrier();
        MEMFENCE;
        #pragma unroll
        for (int i = 0; i < 4; ++i)
            #pragma unroll
            for (int j = 0; j < 4; ++j)
                acc[i][j] = __builtin_amdgcn_mfma_f32_16x16x32_bf16(af[i], bfr[j], acc[i][j], 0, 0, 0);
    }
    // tail: tile 15 in buffer 1
    {
        VMCNT0;
        __builtin_amdgcn_s_barrier();
        MEMFENCE;
        v8bf af[4], bfr[4];
        #pragma unroll
        for (int i = 0; i < 4; ++i) af[i]  = *(v8bf*)&sA[1][wm + i * 16 + mrow][pc];
        #pragma unroll
        for (int j = 0; j < 4; ++j) bfr[j] = *(v8bf*)&sB[1][j * 32 + wn16 + mrow][pc];
        #pragma unroll
        for (int i = 0; i < 4; ++i)
            #pragma unroll
            for (int j = 0; j < 4; ++j)
                acc[i][j] = __builtin_amdgcn_mfma_f32_16x16x32_bf16(af[i], bfr[j], acc[i][j], 0, 0, 0);
    }
    #undef STAGE

    // ---- register-only cell update: lane owns unit u_glob, rows wm+i*16+crow4+r ----
    const int u_glob = u0 + wn16 + mrow;
    const int crow4  = (lane >> 4) * 4;
    float wv[4][4], bs4[4];
    #pragma unroll
    for (int gi = 0; gi < 4; ++gi) {
        float4 wp = *(const float4*)(wih_i + (size_t)(u_glob * 4 + gi) * 4);
        wv[gi][0] = wp.x; wv[gi][1] = wp.y; wv[gi][2] = wp.z; wv[gi][3] = wp.w;
        bs4[gi] = bsum[u_glob * 4 + gi];
    }
    #pragma unroll
    for (int i = 0; i < 4; ++i) {
        const int growb = bm * 128 + wm + i * 16 + crow4;
        #pragma unroll
        for (int r = 0; r < 4; ++r) {
            const int grow = growb + r;
            const float4 x = *(const float4*)(traj + (size_t)grow * (HLEN * IND) + t * IND);
            float g[4];
            #pragma unroll
            for (int gi = 0; gi < 4; ++gi)
                g[gi] = acc[i][gi][r] + bs4[gi]
                      + wv[gi][0] * x.x + wv[gi][1] * x.y + wv[gi][2] * x.z + wv[gi][3] * x.w;
            float ig = sigmf(g[0]);
            float fg = sigmf(g[1]);
            float gg = tanh_fast(g[2]);
            float og = sigmf(g[3]);
            size_t ci = (size_t)grow * HID + u_glob;
            float cn = fg * c[ci] + ig * gg;
            c[ci] = cn;
            h_out[ci] = (__bf16)(og * tanh_fast(cn));
        }
    }
}

// ---------------- projection GEMM: hrel(16384x1024 bf16) = h @ W_rel^T ----------------
__global__ __launch_bounds__(256) void gemm_proj(const __bf16* __restrict__ A,
                                                 const __bf16* __restrict__ Bm,
                                                 __bf16* __restrict__ Cout) {
    __shared__ __bf16 sA[2][128][32];
    __shared__ __bf16 sB[2][128][32];
    const int K = HID, Nn = DD;
    const int tid  = threadIdx.x;
    const int lane = tid & 63;
    const int wave = tid >> 6;
    const int wm = (wave & 1) * 64;
    const int wn = (wave >> 1) * 64;
    const int bn = blockIdx.x;
    const int bm = blockIdx.y;

    v4f acc[4][4] = {};

    const int srow   = tid >> 2;
    const int schunk = (tid & 3) ^ (srow & 3);

    const __bf16* gA = A  + (size_t)(bm * 128 + srow) * K + schunk * 8;
    const __bf16* gB = Bm + (size_t)(bn * 128 + srow) * K + schunk * 8;
    __bf16* lA = &sA[0][0][0] + wave * 512;
    __bf16* lB = &sB[0][0][0] + wave * 512;

    const int mrow = lane & 15;
    const int pc   = ((lane >> 4) ^ (mrow & 3)) * 8;

    #define STAGE(buf, kt)                                        \
        do {                                                      \
            const __bf16* pA_ = gA + (kt) * 32;                   \
            const __bf16* pB_ = gB + (kt) * 32;                   \
            __bf16* dA_ = lA + (buf) * 4096;                      \
            __bf16* dB_ = lB + (buf) * 4096;                      \
            async_copy16(pA_,          dA_);                      \
            async_copy16(pA_ + 64 * K, dA_ + 2048);               \
            async_copy16(pB_,          dB_);                      \
            async_copy16(pB_ + 64 * K, dB_ + 2048);               \
        } while (0)

    STAGE(0, 0);
    #pragma unroll
    for (int k = 0; k < 15; ++k) {
        const int cur = k & 1;
        STAGE(cur ^ 1, k + 1);
        VMCNT4;
        __builtin_amdgcn_s_barrier();
        MEMFENCE;
        v8bf af[4], bfr[4];
        #pragma unroll
        for (int i = 0; i < 4; ++i) af[i]  = *(v8bf*)&sA[cur][wm + i * 16 + mrow][pc];
        #pragma unroll
        for (int j = 0; j < 4; ++j) bfr[j] = *(v8bf*)&sB[cur][wn + j * 16 + mrow][pc];
        LGKM0;
        __builtin_amdgcn_s_barrier();
        MEMFENCE;
        #pragma unroll
        for (int i = 0; i < 4; ++i)
            #pragma unroll
            for (int j = 0; j < 4; ++j)
                acc[i][j] = __builtin_amdgcn_mfma_f32_16x16x32_bf16(af[i], bfr[j], acc[i][j], 0, 0, 0);
    }
    {
        VMCNT0;
        __builtin_amdgcn_s_barrier();
        MEMFENCE;
        v8bf af[4], bfr[4];
        #pragma unroll
        for (int i = 0; i < 4; ++i) af[i]  = *(v8bf*)&sA[1][wm + i * 16 + mrow][pc];
        #pragma unroll
        for (int j = 0; j < 4; ++j) bfr[j] = *(v8bf*)&sB[1][wn + j * 16 + mrow][pc];
        #pragma unroll
        for (int i = 0; i < 4; ++i)
            #pragma unroll
            for (int j = 0; j < 4; ++j)
                acc[i][j] = __builtin_amdgcn_mfma_f32_16x16x32_bf16(af[i], bfr[j], acc[i][j], 0, 0, 0);
    }
    #undef STAGE

    const int ccol  = lane & 15;
    const int crow4 = (lane >> 4) * 4;
    #pragma unroll
    for (int i = 0; i < 4; ++i)
        #pragma unroll
        for (int j = 0; j < 4; ++j) {
            int gm = bm * 128 + wm + i * 16 + crow4;
            int gn = bn * 128 + wn + j * 16 + ccol;
            #pragma unroll
            for (int r = 0; r < 4; ++r)
                Cout[(size_t)(gm + r) * Nn + gn] = (__bf16)acc[i][j][r];
        }
}

// ---------------- fused gate-mix + residual + LayerNorm ----------------
__global__ __launch_bounds__(256) void fuse_ln(const float* __restrict__ tokens,
                                               const __bf16* __restrict__ hrel,
                                               const float* __restrict__ habs_in,
                                               const float* __restrict__ W_abs,
                                               const float* __restrict__ alpha,
                                               const float* __restrict__ gamma,
                                               const float* __restrict__ beta,
                                               float* __restrict__ out) {
    const int row = blockIdx.x;
    const int b   = row >> 9;
    const float al = alpha[b];
    const float a0 = habs_in[(size_t)row * 2];
    const float a1 = habs_in[(size_t)row * 2 + 1];
    const int tid  = threadIdx.x;
    const int lane = tid & 63;
    const int wave = tid >> 6;

    __shared__ float red[4];

    float x[4];
    float s = 0.0f;
    #pragma unroll
    for (int q = 0; q < 4; ++q) {
        int dcol = tid + q * 256;
        float habs = a0 * W_abs[dcol * 2] + a1 * W_abs[dcol * 2 + 1];
        float v = tokens[(size_t)row * DD + dcol]
                + al * (float)hrel[(size_t)row * DD + dcol]
                + (1.0f - al) * habs;
        x[q] = v;
        s += v;
    }
    #pragma unroll
    for (int off = 32; off > 0; off >>= 1) s += __shfl_down(s, off);
    if (lane == 0) red[wave] = s;
    __syncthreads();
    float mu = (red[0] + red[1] + red[2] + red[3]) * (1.0f / DD);

    float vs = 0.0f;
    #pragma unroll
    for (int q = 0; q < 4; ++q) {
        float d = x[q] - mu;
        vs += d * d;
    }
    #pragma unroll
    for (int off = 32; off > 0; off >>= 1) vs += __shfl_down(vs, off);
    __syncthreads();
    if (lane == 0) red[wave] = vs;
    __syncthreads();
    float var = (red[0] + red[1] + red[2] + red[3]) * (1.0f / DD);
    float rstd = rsqrtf(var + EPS);

    #pragma unroll
    for (int q = 0; q < 4; ++q) {
        int dcol = tid + q * 256;
        out[(size_t)row * DD + dcol] = (x[q] - mu) * rstd * gamma[dcol] + beta[dcol];
    }
}

// ---------------- host launch ----------------
extern "C" void kernel_launch(void* const* d_in, const int* in_sizes, int n_in,
                              void* d_out, int out_size, void* d_ws, size_t ws_size,
                              hipStream_t stream) {
    const float* tokens   = (const float*)d_in[0];
    const float* traj     = (const float*)d_in[1];
    const float* habs     = (const float*)d_in[2];
    const float* espeed   = (const float*)d_in[3];
    const float* gconf    = (const float*)d_in[4];
    const float* W_ih     = (const float*)d_in[5];
    const float* W_hh     = (const float*)d_in[6];
    const float* b_ih     = (const float*)d_in[7];
    const float* b_hh     = (const float*)d_in[8];
    const float* W_rel    = (const float*)d_in[9];
    const float* W_abs    = (const float*)d_in[10];
    const float* W_g1     = (const float*)d_in[11];
    const float* b_g1     = (const float*)d_in[12];
    const float* W_g2     = (const float*)d_in[13];
    const float* b_g2     = (const float*)d_in[14];
    const float* gamma    = (const float*)d_in[15];
    const float* beta     = (const float*)d_in[16];
    float* out = (float*)d_out;

    char* ws = (char*)d_ws;
    size_t off = 0;
    __bf16* whh_b  = (__bf16*)(ws + off); off += (size_t)G4 * HID * 2;     // 2 MB
    __bf16* wrel_b = (__bf16*)(ws + off); off += (size_t)DD * HID * 2;     // 1 MB
    float*  wih_i  = (float*)(ws + off);  off += (size_t)G4 * 4 * 4;       // 32 KB
    float*  bsum   = (float*)(ws + off);  off += (size_t)G4 * 4;           // 8 KB
    __bf16* h0     = (__bf16*)(ws + off); off += (size_t)BN * HID * 2;     // 16 MB
    __bf16* h1     = (__bf16*)(ws + off); off += (size_t)BN * HID * 2;     // 16 MB
    float*  c      = (float*)(ws + off);  off += (size_t)BN * HID * 4;     // 32 MB
    __bf16* hrel   = (__bf16*)(ws + off); off += (size_t)BN * DD * 2;      // 32 MB
    float*  alpha  = (float*)(ws + off);  off += 256;

    convert_w<<<(G4 * HID + 255) / 256, 256, 0, stream>>>(W_hh, W_rel, W_ih, b_ih, b_hh,
                                                          whh_b, wrel_b, wih_i, bsum);
    alpha_kernel<<<1, 64, 0, stream>>>(espeed, gconf, W_g1, b_g1, W_g2, b_g2, alpha);
    lstm_cell0<<<(BN * HID) / 256, 256, 0, stream>>>(traj, wih_i, bsum, c, h0);

    __bf16* hbuf[2] = {h0, h1};
    for (int t = 1; t < HLEN; ++t) {
        const __bf16* hin = hbuf[(t + 1) & 1];
        __bf16* hout = hbuf[t & 1];
        gemm_lstm<<<dim3(G4 / 128, BN / 128), 256, 0, stream>>>(hin, whh_b, traj, wih_i, bsum,
                                                                c, hout, t);
    }
    // final h after t=14 is in hbuf[14&1] = h0
    gemm_proj<<<dim3(DD / 128, BN / 128), 256, 0, stream>>>(h0, wrel_b, hrel);
    fuse_ln<<<BN, 256, 0, stream>>>(tokens, hrel, habs, W_abs, alpha, gamma, beta, out);
}

// Round 4
// 1174.407 us; speedup vs baseline: 1.9545x; 1.0942x over previous
//
#include <hip/hip_runtime.h>
#include <hip/hip_bf16.h>
#include <math.h>

// ---------------- problem constants ----------------
#define BB 32
#define NN 512
#define BN 16384          // BB*NN
#define DD 1024
#define HID 512
#define G4 2048           // 4*HID
#define HLEN 15
#define IND 4
#define EPS 1e-5f

typedef __bf16 v8bf __attribute__((ext_vector_type(8)));
typedef float  v4f  __attribute__((ext_vector_type(4)));

__device__ __forceinline__ void async_copy16(const __bf16* gsrc, __bf16* ldst) {
    __builtin_amdgcn_global_load_lds(
        (const __attribute__((address_space(1))) void*)gsrc,
        (__attribute__((address_space(3))) void*)ldst, 16, 0, 0);
}

#define VMCNT4 asm volatile("s_waitcnt vmcnt(4)" ::: "memory")
#define VMCNT0 asm volatile("s_waitcnt vmcnt(0)" ::: "memory")
#define MEMFENCE asm volatile("" ::: "memory")

// fast transcendentals: v_exp_f32 + v_rcp_f32 (rel err ~1e-6, fine vs 0.11 threshold)
#define LOG2E 1.44269504f
__device__ __forceinline__ float sigmf(float x) {
    return __builtin_amdgcn_rcpf(1.0f + __builtin_amdgcn_exp2f(-LOG2E * x));
}
__device__ __forceinline__ float tanh_fast(float x) {
    return 1.0f - 2.0f * __builtin_amdgcn_rcpf(1.0f + __builtin_amdgcn_exp2f(2.0f * LOG2E * x));
}

// ---------------- weight prep ----------------
// whh_b: NATIVE layout bf16 2048x512 (gate blocks i,f,g,o of 512 rows each);
// wrel_b: bf16 1024x512; wih_i: unit-interleaved fp32 2048x4; bsum: b_ih+b_hh interleaved.
__global__ void convert_w(const float* __restrict__ Whh, const float* __restrict__ Wrel,
                          const float* __restrict__ Wih, const float* __restrict__ bih,
                          const float* __restrict__ bhh,
                          __bf16* __restrict__ whh_b, __bf16* __restrict__ wrel_b,
                          float* __restrict__ wih_i, float* __restrict__ bsum) {
    int i = blockIdx.x * 256 + threadIdx.x;
    if (i < G4 * HID) whh_b[i] = (__bf16)Whh[i];
    if (i < DD * HID) wrel_b[i] = (__bf16)Wrel[i];
    if (i < G4) {
        int uu = i >> 2, gi = i & 3;
        int src = gi * HID + uu;
        wih_i[i * 4 + 0] = Wih[src * 4 + 0];
        wih_i[i * 4 + 1] = Wih[src * 4 + 1];
        wih_i[i * 4 + 2] = Wih[src * 4 + 2];
        wih_i[i * 4 + 3] = Wih[src * 4 + 3];
        bsum[i] = bih[src] + bhh[src];
    }
}

// ---------------- per-batch gate alpha ----------------
__global__ void alpha_kernel(const float* __restrict__ es, const float* __restrict__ gc,
                             const float* __restrict__ W_g1, const float* __restrict__ b_g1,
                             const float* __restrict__ W_g2, const float* __restrict__ b_g2,
                             float* __restrict__ alpha) {
    int b = threadIdx.x;
    if (b >= BB) return;
    float c0 = es[b], c1 = gc[b];
    float acc = b_g2[0];
    for (int k = 0; k < 16; ++k) {
        float hk = c0 * W_g1[k * 2] + c1 * W_g1[k * 2 + 1] + b_g1[k];
        hk = fmaxf(hk, 0.0f);
        acc += hk * W_g2[k];
    }
    alpha[b] = 1.0f / (1.0f + expf(-acc));   // once, keep accurate
}

// ---------------- t=0 cell (h0 = c0 = 0 -> gates from input only) ----------------
__global__ __launch_bounds__(256) void lstm_cell0(const float* __restrict__ traj,
                                                  const float* __restrict__ wih_i,
                                                  const float* __restrict__ bsum,
                                                  float* __restrict__ c,
                                                  __bf16* __restrict__ h) {
    int idx = blockIdx.x * 256 + threadIdx.x;   // row*512 + u
    int row = idx >> 9;
    float4 x = *(const float4*)(traj + (size_t)row * (HLEN * IND));   // t = 0, 16B aligned
    int u = idx & 511;
    float g[4];
    #pragma unroll
    for (int gi = 0; gi < 4; ++gi) {
        int j = u * 4 + gi;
        float4 w = *(const float4*)(wih_i + (size_t)j * 4);
        g[gi] = bsum[j] + w.x * x.x + w.y * x.y + w.z * x.z + w.w * x.w;
    }
    float ig = sigmf(g[0]);
    float gg = tanh_fast(g[2]);
    float og = sigmf(g[3]);
    float cn = ig * gg;                    // f*c0 = 0
    c[idx] = cn;
    h[idx] = (__bf16)(og * tanh_fast(cn));
}

// ---------------- fused GEMM + LSTM cell ----------------
// 3-buffer prefetch-distance-2 pipeline, ONE barrier per k-iter:
//   [VMCNT4 -> barrier -> STAGE(k+2) -> ds_read buf[k%3] -> MFMA]
// Safe: a wave's iter-(k-1) ds_reads are consumed (lgkm-waited) by its MFMAs before
// it reaches barrier k, so restaging buf[(k+2)%3]==buf[(k-1)%3] after barrier k is
// race-free. vmcnt(4) leaves tiles k+1 (and soon k+2) in flight across the barrier.
// Bank swizzle (CORRECT, phase-group derivation): ds_read_b128 runs in 4 phases of
// 16 lanes; slot = (row&1)*4 + chunk has 8 slots. chunk ^= (row>>1)&3 makes each
// phase cover all 8 slots twice -> conflict-free. glds dest stays LINEAR; the
// per-lane GLOBAL source chunk is pre-swizzled (both-sides-or-neither, same 64B line).
__global__ __launch_bounds__(256) void gemm_lstm(const __bf16* __restrict__ A,
                                                 const __bf16* __restrict__ Bm,
                                                 const float* __restrict__ traj,
                                                 const float* __restrict__ wih_i,
                                                 const float* __restrict__ bsum,
                                                 float* __restrict__ c,
                                                 __bf16* __restrict__ h_out,
                                                 int t) {
    __shared__ __bf16 sA[3][128][32];   // 3 x 8 KB
    __shared__ __bf16 sB[3][128][32];   //   rows = gate*32 + (u-u0)
    const int K = HID;
    const int tid  = threadIdx.x;
    const int lane = tid & 63;
    const int wave = tid >> 6;
    const int wm   = (wave & 1) * 64;        // row half
    const int wn16 = (wave >> 1) * 16;       // unit half within the block's 32 units
    const int bm = blockIdx.x;               // consecutive blocks sweep rows (L3 reuse)
    const int bn = blockIdx.y;               // units [bn*32, bn*32+32)
    const int u0 = bn * 32;

    v4f acc[4][4] = {};

    const int srow   = tid >> 2;                        // staged row 0..63 (and +64 copy)
    const int schunk = (tid & 3) ^ ((srow >> 1) & 3);   // pre-swizzled source chunk

    const __bf16* gA = A + (size_t)(bm * 128 + srow) * K + schunk * 8;
    // B tile row = gate*32 + uoff; rows srow<64 cover gates 0..1, +64 => +1024 global rows.
    const __bf16* gB = Bm + (size_t)((srow >> 5) * 512 + u0 + (srow & 31)) * K + schunk * 8;
    __bf16* lA = &sA[0][0][0] + wave * 512;   // wave-uniform base; HW scatters lane*16B
    __bf16* lB = &sB[0][0][0] + wave * 512;

    const int mrow = lane & 15;
    const int pc   = ((lane >> 4) ^ ((mrow >> 1) & 3)) * 8;   // swizzled read chunk (elems)

    #define STAGE(buf, kt)                                        \
        do {                                                      \
            const __bf16* pA_ = gA + (kt) * 32;                   \
            const __bf16* pB_ = gB + (kt) * 32;                   \
            __bf16* dA_ = lA + (buf) * 4096;                      \
            __bf16* dB_ = lB + (buf) * 4096;                      \
            async_copy16(pA_,            dA_);                    \
            async_copy16(pA_ + 64 * K,   dA_ + 2048);             \
            async_copy16(pB_,            dB_);                    \
            async_copy16(pB_ + 1024 * K, dB_ + 2048);             \
        } while (0)

    STAGE(0, 0);
    STAGE(1, 1);
    #pragma unroll
    for (int k = 0; k < 16; ++k) {
        if (k < 15) { VMCNT4; } else { VMCNT0; }   // tile k landed; k+1(,k+2) in flight
        __builtin_amdgcn_s_barrier();
        MEMFENCE;
        if (k + 2 < 16) STAGE((k + 2) % 3, k + 2);
        const int cur = k % 3;
        v8bf af[4], bfr[4];
        #pragma unroll
        for (int i = 0; i < 4; ++i) af[i]  = *(v8bf*)&sA[cur][wm + i * 16 + mrow][pc];
        #pragma unroll
        for (int j = 0; j < 4; ++j) bfr[j] = *(v8bf*)&sB[cur][j * 32 + wn16 + mrow][pc];
        #pragma unroll
        for (int i = 0; i < 4; ++i)
            #pragma unroll
            for (int j = 0; j < 4; ++j)
                acc[i][j] = __builtin_amdgcn_mfma_f32_16x16x32_bf16(af[i], bfr[j], acc[i][j], 0, 0, 0);
    }
    #undef STAGE

    // ---- register-only cell update: lane owns unit u_glob, rows wm+i*16+crow4+r ----
    const int u_glob = u0 + wn16 + mrow;
    const int crow4  = (lane >> 4) * 4;
    float wv[4][4], bs4[4];
    #pragma unroll
    for (int gi = 0; gi < 4; ++gi) {
        float4 wp = *(const float4*)(wih_i + (size_t)(u_glob * 4 + gi) * 4);
        wv[gi][0] = wp.x; wv[gi][1] = wp.y; wv[gi][2] = wp.z; wv[gi][3] = wp.w;
        bs4[gi] = bsum[u_glob * 4 + gi];
    }
    #pragma unroll
    for (int i = 0; i < 4; ++i) {
        const int growb = bm * 128 + wm + i * 16 + crow4;
        #pragma unroll
        for (int r = 0; r < 4; ++r) {
            const int grow = growb + r;
            const float4 x = *(const float4*)(traj + (size_t)grow * (HLEN * IND) + t * IND);
            float g[4];
            #pragma unroll
            for (int gi = 0; gi < 4; ++gi)
                g[gi] = acc[i][gi][r] + bs4[gi]
                      + wv[gi][0] * x.x + wv[gi][1] * x.y + wv[gi][2] * x.z + wv[gi][3] * x.w;
            float ig = sigmf(g[0]);
            float fg = sigmf(g[1]);
            float gg = tanh_fast(g[2]);
            float og = sigmf(g[3]);
            size_t ci = (size_t)grow * HID + u_glob;
            float cn = fg * c[ci] + ig * gg;
            c[ci] = cn;
            h_out[ci] = (__bf16)(og * tanh_fast(cn));
        }
    }
}

// ---------------- projection GEMM: hrel(16384x1024 bf16) = h @ W_rel^T ----------------
__global__ __launch_bounds__(256) void gemm_proj(const __bf16* __restrict__ A,
                                                 const __bf16* __restrict__ Bm,
                                                 __bf16* __restrict__ Cout) {
    __shared__ __bf16 sA[3][128][32];
    __shared__ __bf16 sB[3][128][32];
    const int K = HID, Nn = DD;
    const int tid  = threadIdx.x;
    const int lane = tid & 63;
    const int wave = tid >> 6;
    const int wm = (wave & 1) * 64;
    const int wn = (wave >> 1) * 64;
    const int bm = blockIdx.x;
    const int bn = blockIdx.y;

    v4f acc[4][4] = {};

    const int srow   = tid >> 2;
    const int schunk = (tid & 3) ^ ((srow >> 1) & 3);

    const __bf16* gA = A  + (size_t)(bm * 128 + srow) * K + schunk * 8;
    const __bf16* gB = Bm + (size_t)(bn * 128 + srow) * K + schunk * 8;
    __bf16* lA = &sA[0][0][0] + wave * 512;
    __bf16* lB = &sB[0][0][0] + wave * 512;

    const int mrow = lane & 15;
    const int pc   = ((lane >> 4) ^ ((mrow >> 1) & 3)) * 8;

    #define STAGE(buf, kt)                                        \
        do {                                                      \
            const __bf16* pA_ = gA + (kt) * 32;                   \
            const __bf16* pB_ = gB + (kt) * 32;                   \
            __bf16* dA_ = lA + (buf) * 4096;                      \
            __bf16* dB_ = lB + (buf) * 4096;                      \
            async_copy16(pA_,          dA_);                      \
            async_copy16(pA_ + 64 * K, dA_ + 2048);               \
            async_copy16(pB_,          dB_);                      \
            async_copy16(pB_ + 64 * K, dB_ + 2048);               \
        } while (0)

    STAGE(0, 0);
    STAGE(1, 1);
    #pragma unroll
    for (int k = 0; k < 16; ++k) {
        if (k < 15) { VMCNT4; } else { VMCNT0; }
        __builtin_amdgcn_s_barrier();
        MEMFENCE;
        if (k + 2 < 16) STAGE((k + 2) % 3, k + 2);
        const int cur = k % 3;
        v8bf af[4], bfr[4];
        #pragma unroll
        for (int i = 0; i < 4; ++i) af[i]  = *(v8bf*)&sA[cur][wm + i * 16 + mrow][pc];
        #pragma unroll
        for (int j = 0; j < 4; ++j) bfr[j] = *(v8bf*)&sB[cur][wn + j * 16 + mrow][pc];
        #pragma unroll
        for (int i = 0; i < 4; ++i)
            #pragma unroll
            for (int j = 0; j < 4; ++j)
                acc[i][j] = __builtin_amdgcn_mfma_f32_16x16x32_bf16(af[i], bfr[j], acc[i][j], 0, 0, 0);
    }
    #undef STAGE

    const int ccol  = lane & 15;
    const int crow4 = (lane >> 4) * 4;
    #pragma unroll
    for (int i = 0; i < 4; ++i)
        #pragma unroll
        for (int j = 0; j < 4; ++j) {
            int gm = bm * 128 + wm + i * 16 + crow4;
            int gn = bn * 128 + wn + j * 16 + ccol;
            #pragma unroll
            for (int r = 0; r < 4; ++r)
                Cout[(size_t)(gm + r) * Nn + gn] = (__bf16)acc[i][j][r];
        }
}

// ---------------- fused gate-mix + residual + LayerNorm ----------------
__global__ __launch_bounds__(256) void fuse_ln(const float* __restrict__ tokens,
                                               const __bf16* __restrict__ hrel,
                                               const float* __restrict__ habs_in,
                                               const float* __restrict__ W_abs,
                                               const float* __restrict__ alpha,
                                               const float* __restrict__ gamma,
                                               const float* __restrict__ beta,
                                               float* __restrict__ out) {
    const int row = blockIdx.x;
    const int b   = row >> 9;
    const float al = alpha[b];
    const float a0 = habs_in[(size_t)row * 2];
    const float a1 = habs_in[(size_t)row * 2 + 1];
    const int tid  = threadIdx.x;
    const int lane = tid & 63;
    const int wave = tid >> 6;

    __shared__ float red[4];

    float x[4];
    float s = 0.0f;
    #pragma unroll
    for (int q = 0; q < 4; ++q) {
        int dcol = tid + q * 256;
        float habs = a0 * W_abs[dcol * 2] + a1 * W_abs[dcol * 2 + 1];
        float v = tokens[(size_t)row * DD + dcol]
                + al * (float)hrel[(size_t)row * DD + dcol]
                + (1.0f - al) * habs;
        x[q] = v;
        s += v;
    }
    #pragma unroll
    for (int off = 32; off > 0; off >>= 1) s += __shfl_down(s, off);
    if (lane == 0) red[wave] = s;
    __syncthreads();
    float mu = (red[0] + red[1] + red[2] + red[3]) * (1.0f / DD);

    float vs = 0.0f;
    #pragma unroll
    for (int q = 0; q < 4; ++q) {
        float d = x[q] - mu;
        vs += d * d;
    }
    #pragma unroll
    for (int off = 32; off > 0; off >>= 1) vs += __shfl_down(vs, off);
    __syncthreads();
    if (lane == 0) red[wave] = vs;
    __syncthreads();
    float var = (red[0] + red[1] + red[2] + red[3]) * (1.0f / DD);
    float rstd = rsqrtf(var + EPS);

    #pragma unroll
    for (int q = 0; q < 4; ++q) {
        int dcol = tid + q * 256;
        out[(size_t)row * DD + dcol] = (x[q] - mu) * rstd * gamma[dcol] + beta[dcol];
    }
}

// ---------------- host launch ----------------
extern "C" void kernel_launch(void* const* d_in, const int* in_sizes, int n_in,
                              void* d_out, int out_size, void* d_ws, size_t ws_size,
                              hipStream_t stream) {
    const float* tokens   = (const float*)d_in[0];
    const float* traj     = (const float*)d_in[1];
    const float* habs     = (const float*)d_in[2];
    const float* espeed   = (const float*)d_in[3];
    const float* gconf    = (const float*)d_in[4];
    const float* W_ih     = (const float*)d_in[5];
    const float* W_hh     = (const float*)d_in[6];
    const float* b_ih     = (const float*)d_in[7];
    const float* b_hh     = (const float*)d_in[8];
    const float* W_rel    = (const float*)d_in[9];
    const float* W_abs    = (const float*)d_in[10];
    const float* W_g1     = (const float*)d_in[11];
    const float* b_g1     = (const float*)d_in[12];
    const float* W_g2     = (const float*)d_in[13];
    const float* b_g2     = (const float*)d_in[14];
    const float* gamma    = (const float*)d_in[15];
    const float* beta     = (const float*)d_in[16];
    float* out = (float*)d_out;

    char* ws = (char*)d_ws;
    size_t off = 0;
    __bf16* whh_b  = (__bf16*)(ws + off); off += (size_t)G4 * HID * 2;     // 2 MB
    __bf16* wrel_b = (__bf16*)(ws + off); off += (size_t)DD * HID * 2;     // 1 MB
    float*  wih_i  = (float*)(ws + off);  off += (size_t)G4 * 4 * 4;       // 32 KB
    float*  bsum   = (float*)(ws + off);  off += (size_t)G4 * 4;           // 8 KB
    __bf16* h0     = (__bf16*)(ws + off); off += (size_t)BN * HID * 2;     // 16 MB
    __bf16* h1     = (__bf16*)(ws + off); off += (size_t)BN * HID * 2;     // 16 MB
    float*  c      = (float*)(ws + off);  off += (size_t)BN * HID * 4;     // 32 MB
    __bf16* hrel   = (__bf16*)(ws + off); off += (size_t)BN * DD * 2;      // 32 MB
    float*  alpha  = (float*)(ws + off);  off += 256;

    convert_w<<<(G4 * HID + 255) / 256, 256, 0, stream>>>(W_hh, W_rel, W_ih, b_ih, b_hh,
                                                          whh_b, wrel_b, wih_i, bsum);
    alpha_kernel<<<1, 64, 0, stream>>>(espeed, gconf, W_g1, b_g1, W_g2, b_g2, alpha);
    lstm_cell0<<<(BN * HID) / 256, 256, 0, stream>>>(traj, wih_i, bsum, c, h0);

    __bf16* hbuf[2] = {h0, h1};
    for (int t = 1; t < HLEN; ++t) {
        const __bf16* hin = hbuf[(t + 1) & 1];
        __bf16* hout = hbuf[t & 1];
        gemm_lstm<<<dim3(BN / 128, G4 / 128), 256, 0, stream>>>(hin, whh_b, traj, wih_i, bsum,
                                                                c, hout, t);
    }
    // final h after t=14 is in hbuf[14&1] = h0
    gemm_proj<<<dim3(BN / 128, DD / 128), 256, 0, stream>>>(h0, wrel_b, hrel);
    fuse_ln<<<BN, 256, 0, stream>>>(tokens, hrel, habs, W_abs, alpha, gamma, beta, out);
}